// Round 10
// baseline (82.710 us; speedup 1.0000x reference)
//
#include <hip/hip_runtime.h>
#include <math.h>

#define BATCH 2
#define NPTS  1024
#define NC    32
#define DIN   8
#define DOUT  8
#define ATILE 64                          // a's per block (4 waves x 16)
#define NCHUNK 64                         // b-splits
#define BPW   (NPTS / NCHUNK)             // 16 b's per block
#define OUT_ELEMS (BATCH * NPTS * DOUT)   // 16384
#define NE4   (OUT_ELEMS / 4)             // 4096
#define LOG2E 1.4426950408889634f

typedef _Float16 half8 __attribute__((ext_vector_type(8)));
typedef __fp16   fp16x2 __attribute__((ext_vector_type(2)));   // pkrtz return type
typedef float    floatx4 __attribute__((ext_vector_type(4)));

#if __has_builtin(__builtin_amdgcn_exp2f)
#define EXP2F(x) __builtin_amdgcn_exp2f(x)
#else
#define EXP2F(x) exp2f(x)
#endif

// ---------------------------------------------------------------------------
// conv_mfma v2 (R9 fix: cvt_pkrtz returns __fp16x2, not _Float16x2 — pun
// through a union; MFMA operand stays the R8-proven _Float16 half8):
//  - exp2 form: -log2e*(t0-j)^2 = fma(q,j,p) - log2e*j^2 (const per j)
//    -> 2 VALU + 1 trans per basis value.
//  - cvt_pkrtz packs f16 pairs (4 instrs vs 8 cvt+pack). RTZ ok: R8 absmax
//    0.0078 vs threshold 0.0428.
//  - staging reloads W rows from L1 per j (W=8KB, hot) instead of wreg[8][2].
//  - NCHUNK 64 -> 2048 blocks (8/CU supply), BPW=16 serial loop.
//  - MFMA layouts BYTE-IDENTICAL to R8 (verified passing): A m=lane&15,
//    k=quad*8+j; B mirrored n=lane&15; C/D col=lane&15, row=quad*4+reg.
// ---------------------------------------------------------------------------
__global__ __launch_bounds__(256, 4) void conv_mfma(
        const float* __restrict__ feat,
        const float* __restrict__ geo,
        const float* __restrict__ W,
        float*       __restrict__ partial) {  // [NCHUNK][BATCH*NPTS][DOUT]
    __shared__ half8  g_frag[BPW * 64];       // 16 KB: B-frags, [b][lane]
    __shared__ float4 bgeo[BPW];

    const int t     = threadIdx.x;
    const int bid   = blockIdx.x;
    const int chunk = bid & (NCHUNK - 1);
    const int atile = (bid >> 6) & 15;
    const int z     = bid >> 10;

    const int b0 = chunk * BPW;
    const float* geoz  = geo  + (size_t)z * NPTS * 3;
    const float* featz = feat + (size_t)z * NPTS * DIN;

    // ---- zero the never-staged half of each B-frag (n>=8 slots) ----
    for (int s = t; s < BPW * 64; s += 256)
        if (s & 8) {
            half8 zz = {};
            g_frag[s] = zz;
        }

    // ---- stage b geometry ----
    if (t < BPW)
        bgeo[t] = make_float4(geoz[(b0 + t) * 3 + 0],
                              geoz[(b0 + t) * 3 + 1],
                              geoz[(b0 + t) * 3 + 2], 0.f);

    // ---- stage G B-frags: t -> i = t&7, oct = (t>>3)&3, bl = t>>5 ----
    {
        const int i   = t & 7;
        const int oct = (t >> 3) & 3;
        const int bl  = t >> 5;                // 0..7
#pragma unroll
        for (int pass = 0; pass < BPW / 8; ++pass) {
            const int b = pass * 8 + bl;
            const float* f = featz + (size_t)(b0 + b) * DIN;
            const float4 f0 = *(const float4*)f;
            const float4 f1 = *(const float4*)(f + 4);
            half8 gv;
#pragma unroll
            for (int j = 0; j < 8; ++j) {      // W row per j from L1 (8KB, hot)
                const float* wr = W + ((oct * 8 + j) * DOUT + i) * DIN;
                const float4 wa = *(const float4*)wr;
                const float4 wb = *(const float4*)(wr + 4);
                float s = fmaf(wa.x, f0.x,
                          fmaf(wa.y, f0.y,
                          fmaf(wa.z, f0.z,
                          fmaf(wa.w, f0.w,
                          fmaf(wb.x, f1.x,
                          fmaf(wb.y, f1.y,
                          fmaf(wb.z, f1.z,
                                 wb.w * f1.w)))))));
                gv[j] = (_Float16)s;
            }
            g_frag[b * 64 + oct * 16 + i] = gv;
        }
    }
    __syncthreads();

    // ---- main loop: wave wv handles a-subtile a0 = atile*64 + wv*16 ----
    const int lane = t & 63;
    const int wv   = t >> 6;
    const int m    = lane & 15;
    const int quad = lane >> 4;
    const int a0   = atile * ATILE + wv * 16;
    const int a    = a0 + m;

    const float ax = geoz[a * 3 + 0];
    const float ay = geoz[a * 3 + 1];
    const float az = geoz[a * 3 + 2];
    const float c0   = (float)(quad * 8);
    const float invw = (float)(NC - 1) / 3.5f;

    floatx4 acc = {0.f, 0.f, 0.f, 0.f};

#pragma unroll 4
    for (int b = 0; b < BPW; ++b) {
        const float4 bg = bgeo[b];             // broadcast ds_read
        const float dx = bg.x - ax, dy = bg.y - ay, dz = bg.z - az;
        const float u = sqrtf(fmaf(dx, dx, fmaf(dy, dy, fmaf(dz, dz, 1e-12f)))) * invw;
        const float t0 = u - c0;
        // x_j = -log2e*(t0-j)^2 = fma(q, j, p) - log2e*j^2
        const float m1 = t0 * (-LOG2E);
        const float p  = m1 * t0;              // -log2e * t0^2
        const float q  = -2.0f * m1;           //  2*log2e * t0
        float e[8];
#pragma unroll
        for (int j = 0; j < 8; ++j)
            e[j] = EXP2F(fmaf(q, (float)j, p) - LOG2E * (float)(j * j));
        union { half8 v; fp16x2 h[4]; } af;
        af.h[0] = __builtin_amdgcn_cvt_pkrtz(e[0], e[1]);
        af.h[1] = __builtin_amdgcn_cvt_pkrtz(e[2], e[3]);
        af.h[2] = __builtin_amdgcn_cvt_pkrtz(e[4], e[5]);
        af.h[3] = __builtin_amdgcn_cvt_pkrtz(e[6], e[7]);
        const half8 bfrg = g_frag[b * 64 + lane];   // per-lane ds_read_b128
        acc = __builtin_amdgcn_mfma_f32_16x16x32_f16(af.v, bfrg, acc, 0, 0, 0);
    }

    // ---- epilogue: D col = i (lane&15, keep <8), row = quad*4 + reg ----
    if (m < 8) {
        float* p = partial + (size_t)chunk * OUT_ELEMS
                 + ((size_t)(z * NPTS + a0 + quad * 4)) * DOUT + m;
#pragma unroll
        for (int r = 0; r < 4; ++r)
            p[r * DOUT] = acc[r];
    }
}

// ---------------------------------------------------------------------------
// reduce_partials: 256 blocks, 16 f4-elems x 16 chunk-groups; each thread
// sums NCH/16 independent loads, then 16-way LDS reduction.
// ---------------------------------------------------------------------------
template <int NCH>
__global__ __launch_bounds__(256) void reduce_partials(
        const float* __restrict__ partial,
        const int*   __restrict__ n_norm,
        float*       __restrict__ out) {
    const int tx = threadIdx.x & 15;
    const int ty = threadIdx.x >> 4;
    const int e4 = blockIdx.x * 16 + tx;
    const float4* p = (const float4*)partial;

    float4 s = make_float4(0.f, 0.f, 0.f, 0.f);
#pragma unroll
    for (int j = 0; j < NCH / 16; ++j) {
        float4 v = p[(size_t)(j * 16 + ty) * NE4 + e4];
        s.x += v.x; s.y += v.y; s.z += v.z; s.w += v.w;
    }

    __shared__ float4 red[16][16];
    red[ty][tx] = s;
    __syncthreads();

    if (ty == 0) {
        float4 tot = red[0][tx];
#pragma unroll
        for (int j = 1; j < 16; ++j) {
            float4 v = red[j][tx];
            tot.x += v.x; tot.y += v.y; tot.z += v.z; tot.w += v.w;
        }
        const float scale = 1.0f / sqrtf((float)n_norm[0]);
        ((float4*)out)[e4] = make_float4(tot.x * scale, tot.y * scale,
                                         tot.z * scale, tot.w * scale);
    }
}

// ---------------------------------------------------------------------------
extern "C" void kernel_launch(void* const* d_in, const int* in_sizes, int n_in,
                              void* d_out, int out_size, void* d_ws, size_t ws_size,
                              hipStream_t stream) {
    const float* feat   = (const float*)d_in[0];   // [2,1024,8]
    const float* geo    = (const float*)d_in[1];   // [2,1024,3]
    const float* W      = (const float*)d_in[2];   // [32,8,8]
    const int*   n_norm = (const int*)  d_in[3];   // scalar 1024
    float* out     = (float*)d_out;                // [2,1024,8]
    float* partial = (float*)d_ws;                 // 64 * 64 KB = 4 MB

    const int grid = BATCH * 16 * NCHUNK;          // 2048 blocks
    conv_mfma<<<grid, 256, 0, stream>>>(feat, geo, W, partial);
    reduce_partials<NCHUNK><<<NE4 / 16, 256, 0, stream>>>(partial, n_norm, out);
}

// Round 11
// 78.342 us; speedup vs baseline: 1.0558x; 1.0558x over previous
//
#include <hip/hip_runtime.h>
#include <math.h>

#define BATCH 2
#define NPTS  1024
#define NC    32
#define DIN   8
#define DOUT  8
#define ATILE 64                          // a's per block (4 waves x 16)
#define NCHUNK 32                         // b-splits
#define BPW   (NPTS / NCHUNK)             // 32 b's per block
#define OUT_ELEMS (BATCH * NPTS * DOUT)   // 16384
#define NE4   (OUT_ELEMS / 4)             // 4096
#define LOG2E 1.4426950408889634f
#define G_BYTES ((size_t)BATCH * NPTS * 64 * 16)   // 2 MB of half8 B-frags

typedef _Float16 half8 __attribute__((ext_vector_type(8)));
typedef __fp16   fp16x2 __attribute__((ext_vector_type(2)));
typedef float    floatx4 __attribute__((ext_vector_type(4)));

#if __has_builtin(__builtin_amdgcn_exp2f)
#define EXP2F(x) __builtin_amdgcn_exp2f(x)
#else
#define EXP2F(x) exp2f(x)
#endif

// ---------------------------------------------------------------------------
// g_kernel: one-time build of B-frags in ws.
// Slot layout per b (64 half8 slots, one per lane): slot = oct*16 + i for
// i<8 holds G[c=oct*8+j][i], j=0..7; slots with (slot&8) are the n>=8 half
// of the MFMA B operand -> zero. Byte-identical to what R8/R10 staged in LDS.
// ---------------------------------------------------------------------------
__global__ __launch_bounds__(256) void g_kernel(
        const float* __restrict__ feat,
        const float* __restrict__ W,
        half8*       __restrict__ gws) {
    const int e    = blockIdx.x * 256 + threadIdx.x;  // < BATCH*NPTS*64
    const int slot = e & 63;
    const int zb   = e >> 6;
    half8 gv = {};
    if (!(slot & 8)) {
        const int i   = slot & 7;
        const int oct = slot >> 4;
        const float* f = feat + (size_t)zb * DIN;
        const float4 f0 = *(const float4*)f;
        const float4 f1 = *(const float4*)(f + 4);
#pragma unroll
        for (int j = 0; j < 8; ++j) {
            const float* wr = W + ((oct * 8 + j) * DOUT + i) * DIN;
            const float4 wa = *(const float4*)wr;
            const float4 wb = *(const float4*)(wr + 4);
            float s = fmaf(wa.x, f0.x,
                      fmaf(wa.y, f0.y,
                      fmaf(wa.z, f0.z,
                      fmaf(wa.w, f0.w,
                      fmaf(wb.x, f1.x,
                      fmaf(wb.y, f1.y,
                      fmaf(wb.z, f1.z,
                             wb.w * f1.w)))))));
            gv[j] = (_Float16)s;               // RNE
        }
    }
    gws[e] = gv;                               // 16B/thread coalesced
}

// ---------------------------------------------------------------------------
// conv_mfma v3 — NO LDS, NO BARRIER, NO PER-BLOCK STAGING (R10 diagnosis:
// conv ~35us vs ~6us issue model; block prologue [LDS zero-fill + global
// W/feat loads + __syncthreads over a 16-iter loop] dominated; R6's one
// visible counter set showed Occupancy 17%).
// Body per b: uniform s_load b-geom -> dist -> 8 exp2 -> pkrtz pack ->
// per-lane global_load_dwordx4 of the B-frag (L1-hot, 4 waves/block share
// one 32KB chunk) -> MFMA. Dual accumulators break the MFMA dep chain.
// Layouts byte-identical to R8/R10 (verified passing).
// ---------------------------------------------------------------------------
__global__ __launch_bounds__(256, 4) void conv_mfma(
        const float* __restrict__ geo,
        const half8* __restrict__ gws,
        float*       __restrict__ partial) {  // [NCHUNK][BATCH*NPTS][DOUT]
    const int t     = threadIdx.x;
    const int bid   = blockIdx.x;
    const int chunk = bid & (NCHUNK - 1);
    const int atile = (bid >> 5) & 15;
    const int z     = bid >> 9;

    const int b0 = chunk * BPW;
    const float* geoz = geo + (size_t)z * NPTS * 3;

    const int lane = t & 63;
    const int wv   = t >> 6;
    const int m    = lane & 15;
    const int quad = lane >> 4;
    const int a0   = atile * ATILE + wv * 16;
    const int a    = a0 + m;

    const float ax = geoz[a * 3 + 0];
    const float ay = geoz[a * 3 + 1];
    const float az = geoz[a * 3 + 2];
    const float c0   = (float)(quad * 8);
    const float invw = (float)(NC - 1) / 3.5f;

    const half8* gp = gws + ((size_t)(z * NPTS + b0)) * 64 + lane;

    floatx4 acc0 = {0.f, 0.f, 0.f, 0.f};
    floatx4 acc1 = {0.f, 0.f, 0.f, 0.f};

#pragma unroll 8
    for (int b = 0; b < BPW; ++b) {
        // wave-uniform b-geometry -> scalar loads, prefetched by unroll
        const float bx = geoz[(b0 + b) * 3 + 0];
        const float by = geoz[(b0 + b) * 3 + 1];
        const float bz = geoz[(b0 + b) * 3 + 2];
        const float dx = bx - ax, dy = by - ay, dz = bz - az;
        const float u  = sqrtf(fmaf(dx, dx, fmaf(dy, dy, fmaf(dz, dz, 1e-12f)))) * invw;
        const float t0 = u - c0;
        // -log2e*(t0-j)^2 = fma(q,j,p) - log2e*j^2 (last term compile-const)
        const float m1 = t0 * (-LOG2E);
        const float p  = m1 * t0;
        const float q  = -2.0f * m1;
        float e[8];
#pragma unroll
        for (int j = 0; j < 8; ++j)
            e[j] = EXP2F(fmaf(q, (float)j, p) - LOG2E * (float)(j * j));
        union { half8 v; fp16x2 h[4]; } af;
        af.h[0] = __builtin_amdgcn_cvt_pkrtz(e[0], e[1]);
        af.h[1] = __builtin_amdgcn_cvt_pkrtz(e[2], e[3]);
        af.h[2] = __builtin_amdgcn_cvt_pkrtz(e[4], e[5]);
        af.h[3] = __builtin_amdgcn_cvt_pkrtz(e[6], e[7]);
        const half8 bfrg = gp[(size_t)b * 64];     // global_load_dwordx4, L1-hot
        if (b & 1)
            acc1 = __builtin_amdgcn_mfma_f32_16x16x32_f16(af.v, bfrg, acc1, 0, 0, 0);
        else
            acc0 = __builtin_amdgcn_mfma_f32_16x16x32_f16(af.v, bfrg, acc0, 0, 0, 0);
    }

    // ---- epilogue: D col = i (lane&15, keep <8), row = quad*4 + reg ----
    if (m < 8) {
        float* pp = partial + (size_t)chunk * OUT_ELEMS
                  + ((size_t)(z * NPTS + a0 + quad * 4)) * DOUT + m;
#pragma unroll
        for (int r = 0; r < 4; ++r)
            pp[r * DOUT] = acc0[r] + acc1[r];
    }
}

// ---------------------------------------------------------------------------
// reduce_partials: 256 blocks, 16 f4-elems x 16 chunk-groups; each thread
// sums NCH/16 independent loads, then 16-way LDS reduction.
// ---------------------------------------------------------------------------
template <int NCH>
__global__ __launch_bounds__(256) void reduce_partials(
        const float* __restrict__ partial,
        const int*   __restrict__ n_norm,
        float*       __restrict__ out) {
    const int tx = threadIdx.x & 15;
    const int ty = threadIdx.x >> 4;
    const int e4 = blockIdx.x * 16 + tx;
    const float4* p = (const float4*)partial;

    float4 s = make_float4(0.f, 0.f, 0.f, 0.f);
#pragma unroll
    for (int j = 0; j < NCH / 16; ++j) {
        float4 v = p[(size_t)(j * 16 + ty) * NE4 + e4];
        s.x += v.x; s.y += v.y; s.z += v.z; s.w += v.w;
    }

    __shared__ float4 red[16][16];
    red[ty][tx] = s;
    __syncthreads();

    if (ty == 0) {
        float4 tot = red[0][tx];
#pragma unroll
        for (int j = 1; j < 16; ++j) {
            float4 v = red[j][tx];
            tot.x += v.x; tot.y += v.y; tot.z += v.z; tot.w += v.w;
        }
        const float scale = 1.0f / sqrtf((float)n_norm[0]);
        ((float4*)out)[e4] = make_float4(tot.x * scale, tot.y * scale,
                                         tot.z * scale, tot.w * scale);
    }
}

// ---------------------------------------------------------------------------
extern "C" void kernel_launch(void* const* d_in, const int* in_sizes, int n_in,
                              void* d_out, int out_size, void* d_ws, size_t ws_size,
                              hipStream_t stream) {
    const float* feat   = (const float*)d_in[0];   // [2,1024,8]
    const float* geo    = (const float*)d_in[1];   // [2,1024,3]
    const float* W      = (const float*)d_in[2];   // [32,8,8]
    const int*   n_norm = (const int*)  d_in[3];   // scalar 1024
    float* out = (float*)d_out;                    // [2,1024,8]

    half8* gws     = (half8*)d_ws;                              // 2 MB
    float* partial = (float*)((char*)d_ws + G_BYTES);           // 2 MB

    g_kernel<<<(BATCH * NPTS * 64) / 256, 256, 0, stream>>>(feat, W, gws);
    conv_mfma<<<BATCH * 16 * NCHUNK, 256, 0, stream>>>(geo, gws, partial);
    reduce_partials<NCHUNK><<<NE4 / 16, 256, 0, stream>>>(partial, n_norm, out);
}

// Round 12
// 75.522 us; speedup vs baseline: 1.0952x; 1.0373x over previous
//
#include <hip/hip_runtime.h>
#include <math.h>

#define BATCH 2
#define NPTS  1024
#define NC    32
#define DIN   8
#define DOUT  8
#define ATILE 64                          // a's per block (4 waves x 16)
#define NCHUNK 64                         // b-splits
#define BPW   (NPTS / NCHUNK)             // 16 b's per block
#define OUT_ELEMS (BATCH * NPTS * DOUT)   // 16384
#define NE4   (OUT_ELEMS / 4)             // 4096
#define LOG2E 1.4426950408889634f
#define G_BYTES ((size_t)BATCH * NPTS * 64 * 16)   // 2 MB of half8 B-frags

typedef _Float16 half8 __attribute__((ext_vector_type(8)));
typedef __fp16   fp16x2 __attribute__((ext_vector_type(2)));
typedef float    floatx4 __attribute__((ext_vector_type(4)));

#if __has_builtin(__builtin_amdgcn_exp2f)
#define EXP2F(x) __builtin_amdgcn_exp2f(x)
#else
#define EXP2F(x) exp2f(x)
#endif

// ---------------------------------------------------------------------------
// g_kernel (unchanged, R11-verified): one-time build of B-frags in ws.
// Slot layout per b: slot = oct*16 + i (i<8) holds G[c=oct*8+j][i], j=0..7;
// slots with (slot&8) are the n>=8 half of the B operand -> zero.
// ---------------------------------------------------------------------------
__global__ __launch_bounds__(256) void g_kernel(
        const float* __restrict__ feat,
        const float* __restrict__ W,
        half8*       __restrict__ gws) {
    const int e    = blockIdx.x * 256 + threadIdx.x;  // < BATCH*NPTS*64
    const int slot = e & 63;
    const int zb   = e >> 6;
    half8 gv = {};
    if (!(slot & 8)) {
        const int i   = slot & 7;
        const int oct = slot >> 4;
        const float* f = feat + (size_t)zb * DIN;
        const float4 f0 = *(const float4*)f;
        const float4 f1 = *(const float4*)(f + 4);
#pragma unroll
        for (int j = 0; j < 8; ++j) {
            const float* wr = W + ((oct * 8 + j) * DOUT + i) * DIN;
            const float4 wa = *(const float4*)wr;
            const float4 wb = *(const float4*)(wr + 4);
            float s = fmaf(wa.x, f0.x,
                      fmaf(wa.y, f0.y,
                      fmaf(wa.z, f0.z,
                      fmaf(wa.w, f0.w,
                      fmaf(wb.x, f1.x,
                      fmaf(wb.y, f1.y,
                      fmaf(wb.z, f1.z,
                             wb.w * f1.w)))))));
            gv[j] = (_Float16)s;
        }
    }
    gws[e] = gv;
}

// ---------------------------------------------------------------------------
// conv_mfma v4 — attack the TRANS pipe (R11 diagnosis: conv ~34us, issue
// model 140 cyc/wave-b of which 72 = sqrt + 8 v_exp at 1/4 rate = 51%).
// Dual-seed exp recurrence: seeds e0=exp(-tc^2), e4=exp(-(tc-4)^2), ratio
// r0=exp(2tc-1), r4=r0*exp(-8); chains of <=3 muls each:
//   e_{j+1}=e_j*r_j, r_{j+1}=r_j*exp(-2).
// NaN/underflow proof:
//  * upper clamp tc=min(t0,11): t0>11 => all true values <= exp(-16)~=0;
//    r0=exp(21) finite, e0=exp(-121)=+0 -> 0*finite=0 (no 0*inf, the R7 bug).
//  * no lower clamp needed: t0<<0 => e0 underflows to 0, r0 underflows
//    benignly, chain stays 0 = true value.
//  * seed-dead-tail-alive impossible: each chain is <=3 steps from its seed,
//    so seed underflow (|t_seed|>9.3) implies all its values <= exp(-40).
// Trans/b: 9 -> 4 (sqrt + 3 exp2). Predicted issue ~100 cyc/wave-b.
// NCHUNK 64 -> 2048 blocks (8/CU); full unroll folds uniform geo reads into
// batched s_loads. Layouts byte-identical to R8/R10/R11 (verified).
// ---------------------------------------------------------------------------
__global__ __launch_bounds__(256, 4) void conv_mfma(
        const float* __restrict__ geo,
        const half8* __restrict__ gws,
        float*       __restrict__ partial) {  // [NCHUNK][BATCH*NPTS][DOUT]
    const int t     = threadIdx.x;
    const int bid   = blockIdx.x;
    const int chunk = bid & (NCHUNK - 1);
    const int atile = (bid >> 6) & 15;
    const int z     = bid >> 10;

    const int b0 = chunk * BPW;
    const float* geoz = geo + (size_t)z * NPTS * 3;
    const float* bge  = geoz + b0 * 3;         // wave-uniform base

    const int lane = t & 63;
    const int wv   = t >> 6;
    const int m    = lane & 15;
    const int quad = lane >> 4;
    const int a0   = atile * ATILE + wv * 16;
    const int a    = a0 + m;

    const float ax = geoz[a * 3 + 0];
    const float ay = geoz[a * 3 + 1];
    const float az = geoz[a * 3 + 2];
    const float c0   = (float)(quad * 8);
    const float invw = (float)(NC - 1) / 3.5f;
    const float K2   = 0.13533528324f;         // exp(-2)
    const float K8   = 3.35462627903e-4f;      // exp(-8)

    const half8* gp = gws + ((size_t)(z * NPTS + b0)) * 64 + lane;

    floatx4 acc0 = {0.f, 0.f, 0.f, 0.f};
    floatx4 acc1 = {0.f, 0.f, 0.f, 0.f};

#pragma unroll
    for (int b = 0; b < BPW; ++b) {
        // wave-uniform geo (compile-time offsets under full unroll -> s_load)
        const float bx = bge[b * 3 + 0];
        const float by = bge[b * 3 + 1];
        const float bz = bge[b * 3 + 2];
        const float dx = bx - ax, dy = by - ay, dz = bz - az;
        const float u  = sqrtf(fmaf(dx, dx, fmaf(dy, dy, fmaf(dz, dz, 1e-12f)))) * invw;
        const float tc = fminf(u - c0, 11.0f);
        // seeds + ratios
        const float e0 = EXP2F((tc * tc) * (-LOG2E));
        const float t4 = tc - 4.0f;
        const float e4 = EXP2F((t4 * t4) * (-LOG2E));
        const float r0 = EXP2F(fmaf(2.0f * LOG2E, tc, -LOG2E));   // exp(2tc-1)
        const float r4 = r0 * K8;                                  // exp(2t4-1)
        // chains (<=3 muls from each seed)
        const float e1 = e0 * r0;  const float r1 = r0 * K2;
        const float e2 = e1 * r1;  const float r2 = r1 * K2;
        const float e3 = e2 * r2;
        const float e5 = e4 * r4;  const float r5 = r4 * K2;
        const float e6 = e5 * r5;  const float r6 = r5 * K2;
        const float e7 = e6 * r6;
        union { half8 v; fp16x2 h[4]; } af;
        af.h[0] = __builtin_amdgcn_cvt_pkrtz(e0, e1);
        af.h[1] = __builtin_amdgcn_cvt_pkrtz(e2, e3);
        af.h[2] = __builtin_amdgcn_cvt_pkrtz(e4, e5);
        af.h[3] = __builtin_amdgcn_cvt_pkrtz(e6, e7);
        const half8 bfrg = gp[(size_t)b * 64];     // global_load_dwordx4, L1-hot
        if (b & 1)
            acc1 = __builtin_amdgcn_mfma_f32_16x16x32_f16(af.v, bfrg, acc1, 0, 0, 0);
        else
            acc0 = __builtin_amdgcn_mfma_f32_16x16x32_f16(af.v, bfrg, acc0, 0, 0, 0);
    }

    // ---- epilogue: D col = i (lane&15, keep <8), row = quad*4 + reg ----
    if (m < 8) {
        float* pp = partial + (size_t)chunk * OUT_ELEMS
                  + ((size_t)(z * NPTS + a0 + quad * 4)) * DOUT + m;
#pragma unroll
        for (int r = 0; r < 4; ++r)
            pp[r * DOUT] = acc0[r] + acc1[r];
    }
}

// ---------------------------------------------------------------------------
// reduce_partials: 256 blocks, 16 f4-elems x 16 chunk-groups; each thread
// sums NCH/16 independent loads, then 16-way LDS reduction.
// ---------------------------------------------------------------------------
template <int NCH>
__global__ __launch_bounds__(256) void reduce_partials(
        const float* __restrict__ partial,
        const int*   __restrict__ n_norm,
        float*       __restrict__ out) {
    const int tx = threadIdx.x & 15;
    const int ty = threadIdx.x >> 4;
    const int e4 = blockIdx.x * 16 + tx;
    const float4* p = (const float4*)partial;

    float4 s = make_float4(0.f, 0.f, 0.f, 0.f);
#pragma unroll
    for (int j = 0; j < NCH / 16; ++j) {
        float4 v = p[(size_t)(j * 16 + ty) * NE4 + e4];
        s.x += v.x; s.y += v.y; s.z += v.z; s.w += v.w;
    }

    __shared__ float4 red[16][16];
    red[ty][tx] = s;
    __syncthreads();

    if (ty == 0) {
        float4 tot = red[0][tx];
#pragma unroll
        for (int j = 1; j < 16; ++j) {
            float4 v = red[j][tx];
            tot.x += v.x; tot.y += v.y; tot.z += v.z; tot.w += v.w;
        }
        const float scale = 1.0f / sqrtf((float)n_norm[0]);
        ((float4*)out)[e4] = make_float4(tot.x * scale, tot.y * scale,
                                         tot.z * scale, tot.w * scale);
    }
}

// ---------------------------------------------------------------------------
extern "C" void kernel_launch(void* const* d_in, const int* in_sizes, int n_in,
                              void* d_out, int out_size, void* d_ws, size_t ws_size,
                              hipStream_t stream) {
    const float* feat   = (const float*)d_in[0];   // [2,1024,8]
    const float* geo    = (const float*)d_in[1];   // [2,1024,3]
    const float* W      = (const float*)d_in[2];   // [32,8,8]
    const int*   n_norm = (const int*)  d_in[3];   // scalar 1024
    float* out = (float*)d_out;                    // [2,1024,8]

    half8* gws     = (half8*)d_ws;                              // 2 MB
    float* partial = (float*)((char*)d_ws + G_BYTES);           // 4 MB

    g_kernel<<<(BATCH * NPTS * 64) / 256, 256, 0, stream>>>(feat, W, gws);
    conv_mfma<<<BATCH * 16 * NCHUNK, 256, 0, stream>>>(geo, gws, partial);
    reduce_partials<NCHUNK><<<NE4 / 16, 256, 0, stream>>>(partial, n_norm, out);
}